// Round 1
// baseline (44.200 us; speedup 1.0000x reference)
//
#include <hip/hip_runtime.h>

// RX gate on wire 0 of a 24-qubit state (N = 2^24 amplitudes).
// Pairs (i, i+H), H = N/2. c = cos(th/2), s = -i*sin(th/2).
// out layout: [2, N] float32 — out[0..N) = real, out[N..2N) = imag.

constexpr int kN = 1 << 24;
constexpr int kH = kN >> 1;        // 8388608
constexpr int kH4 = kH >> 2;       // float4 count per half = 2097152

__global__ __launch_bounds__(256) void rx_wire0_kernel(
    const float4* __restrict__ xr,
    const float4* __restrict__ xi,
    const float* __restrict__ angle,
    float* __restrict__ out)
{
    const int t = blockIdx.x * blockDim.x + threadIdx.x; // float4 index in [0, kH4)
    if (t >= kH4) return;

    const float th = angle[0] * 0.5f;   // wave-uniform scalar
    const float c  = cosf(th);
    const float sn = sinf(th);

    float4* __restrict__ out_re = reinterpret_cast<float4*>(out);
    float4* __restrict__ out_im = reinterpret_cast<float4*>(out + kN);

    // loads: all four streams coalesced (contiguous within each half)
    const float4 arl = xr[t];        // x_real[i..i+3],     i = 4t
    const float4 arh = xr[t + kH4];  // x_real[i+H..i+H+3]
    const float4 ail = xi[t];        // x_imag[i..i+3]
    const float4 aih = xi[t + kH4];  // x_imag[i+H..i+H+3]

    float4 orl, orh, oil, oih;
    orl.x = c * arl.x + sn * aih.x;  oil.x = c * ail.x - sn * arh.x;
    orl.y = c * arl.y + sn * aih.y;  oil.y = c * ail.y - sn * arh.y;
    orl.z = c * arl.z + sn * aih.z;  oil.z = c * ail.z - sn * arh.z;
    orl.w = c * arl.w + sn * aih.w;  oil.w = c * ail.w - sn * arh.w;

    orh.x = c * arh.x + sn * ail.x;  oih.x = c * aih.x - sn * arl.x;
    orh.y = c * arh.y + sn * ail.y;  oih.y = c * aih.y - sn * arl.y;
    orh.z = c * arh.z + sn * ail.z;  oih.z = c * aih.z - sn * arl.z;
    orh.w = c * arh.w + sn * ail.w;  oih.w = c * aih.w - sn * arl.w;

    out_re[t]       = orl;
    out_re[t + kH4] = orh;
    out_im[t]       = oil;
    out_im[t + kH4] = oih;
}

extern "C" void kernel_launch(void* const* d_in, const int* in_sizes, int n_in,
                              void* d_out, int out_size, void* d_ws, size_t ws_size,
                              hipStream_t stream) {
    const float4* xr = reinterpret_cast<const float4*>(d_in[0]);
    const float4* xi = reinterpret_cast<const float4*>(d_in[1]);
    const float* angle = reinterpret_cast<const float*>(d_in[2]);
    float* out = reinterpret_cast<float*>(d_out);

    const int threads = 256;
    const int blocks = kH4 / threads; // 8192
    rx_wire0_kernel<<<blocks, threads, 0, stream>>>(xr, xi, angle, out);
}

// Round 3
// 43.830 us; speedup vs baseline: 1.0084x; 1.0084x over previous
//
#include <hip/hip_runtime.h>

// RX gate on wire 0 of a 24-qubit state (N = 2^24 amplitudes).
// Pairs (i, i+H), H = N/2. c = cos(th/2), s = -i*sin(th/2).
// out layout: [2, N] float32 — out[0..N) = real, out[N..2N) = imag.
//
// R3: nontemporal stores via clang ext_vector_type (HIP_vector_type structs
// are rejected by __builtin_nontemporal_store). Output is write-once/never
// re-read; nt (evict-first) should keep the 128 MB input L3-resident across
// graph replays -> reads at L3 BW, HBM pays only the write stream.

constexpr int kN = 1 << 24;
constexpr int kH = kN >> 1;        // 8388608
constexpr int kH4 = kH >> 2;       // float4 count per half = 2097152

typedef float floatx4 __attribute__((ext_vector_type(4)));

__global__ __launch_bounds__(256) void rx_wire0_kernel(
    const floatx4* __restrict__ xr,
    const floatx4* __restrict__ xi,
    const float* __restrict__ angle,
    float* __restrict__ out)
{
    const int t = blockIdx.x * blockDim.x + threadIdx.x; // float4 index in [0, kH4)
    if (t >= kH4) return;

    const float th = angle[0] * 0.5f;   // wave-uniform scalar
    const float c  = cosf(th);
    const float sn = sinf(th);

    floatx4* __restrict__ out_re = reinterpret_cast<floatx4*>(out);
    floatx4* __restrict__ out_im = reinterpret_cast<floatx4*>(out + kN);

    // loads: all four streams coalesced (contiguous within each half)
    const floatx4 arl = xr[t];        // x_real[i..i+3],     i = 4t
    const floatx4 arh = xr[t + kH4];  // x_real[i+H..i+H+3]
    const floatx4 ail = xi[t];        // x_imag[i..i+3]
    const floatx4 aih = xi[t + kH4];  // x_imag[i+H..i+H+3]

    const floatx4 orl = c * arl + sn * aih;
    const floatx4 oil = c * ail - sn * arh;
    const floatx4 orh = c * arh + sn * ail;
    const floatx4 oih = c * aih - sn * arl;

    __builtin_nontemporal_store(orl, &out_re[t]);
    __builtin_nontemporal_store(orh, &out_re[t + kH4]);
    __builtin_nontemporal_store(oil, &out_im[t]);
    __builtin_nontemporal_store(oih, &out_im[t + kH4]);
}

extern "C" void kernel_launch(void* const* d_in, const int* in_sizes, int n_in,
                              void* d_out, int out_size, void* d_ws, size_t ws_size,
                              hipStream_t stream) {
    const floatx4* xr = reinterpret_cast<const floatx4*>(d_in[0]);
    const floatx4* xi = reinterpret_cast<const floatx4*>(d_in[1]);
    const float* angle = reinterpret_cast<const float*>(d_in[2]);
    float* out = reinterpret_cast<float*>(d_out);

    const int threads = 256;
    const int blocks = kH4 / threads; // 8192
    rx_wire0_kernel<<<blocks, threads, 0, stream>>>(xr, xi, angle, out);
}